// Round 1
// baseline (487.978 us; speedup 1.0000x reference)
//
#include <hip/hip_runtime.h>
#include <hip/hip_bf16.h>

typedef __bf16 bf16;
typedef __bf16 bf16x8 __attribute__((ext_vector_type(8)));
typedef float floatx4 __attribute__((ext_vector_type(4)));

#define MFMA_16x16x32(a, b, c) __builtin_amdgcn_mfma_f32_16x16x32_bf16((a), (b), (c), 0, 0, 0)
#define NEG_INF (-__builtin_inff())

// ---------------------------------------------------------------------------
// GEMM: C = (A @ W + bias) * scale
//   A: [M,K] fp32 (ABF=false) or bf16 (ABF=true), row-major
//   W: [K,N] fp32 row-major
//   mode 0: store bf16 scattered to [B, H, S, 64] head-major (Q/K/V)
//   mode 1: store fp32 row-major [M, N] (final projection -> d_out)
// Block: 256 thr (4 waves), tile 64x64, BK=32, mfma_f32_16x16x32_bf16.
// C/D layout: col = lane&15, row = (lane>>4)*4 + reg  (verified m89/m91).
// A frag: A[m=lane&15][k=(lane>>4)*8+j]; B frag: B[k=(lane>>4)*8+j][n=lane&15].
// ---------------------------------------------------------------------------
template <bool ABF>
__global__ __launch_bounds__(256) void gemm_mfma(
    const void* __restrict__ Aptr, const float* __restrict__ W,
    const float* __restrict__ bias, void* __restrict__ Out,
    int M, int N, int K, int mode, float scale, int S)
{
    __shared__ bf16 As[64 * 40];   // [row][k], pad 32->40 to break bank aliasing
    __shared__ bf16 Bs[64 * 40];   // [n][k]   (W staged transposed)

    const int t = threadIdx.x;
    const int wave = t >> 6, lane = t & 63;
    const int quad = lane >> 4, l15 = lane & 15;
    const int bm = blockIdx.y * 64, bn = blockIdx.x * 64;
    const int waveM = (wave >> 1) * 32, waveN = (wave & 1) * 32;

    floatx4 acc[2][2] = {};

    const int arow = t >> 2, akp = (t & 3) * 8;   // A tile: 64 rows x 32 k
    const int bk = t >> 3, bnp = (t & 7) * 8;     // W tile: 32 k  x 64 n

    for (int k0 = 0; k0 < K; k0 += 32) {
        // ---- stage A tile (fp32 -> bf16 convert in-flight if needed)
        if (ABF) {
            const bf16* A = (const bf16*)Aptr;
            *(bf16x8*)&As[arow * 40 + akp] =
                *(const bf16x8*)(A + (size_t)(bm + arow) * K + k0 + akp);
        } else {
            const float* A = (const float*)Aptr;
            const float* src = A + (size_t)(bm + arow) * K + k0 + akp;
            float4 v0 = *(const float4*)src;
            float4 v1 = *(const float4*)(src + 4);
            bf16x8 v;
            v[0] = (bf16)v0.x; v[1] = (bf16)v0.y; v[2] = (bf16)v0.z; v[3] = (bf16)v0.w;
            v[4] = (bf16)v1.x; v[5] = (bf16)v1.y; v[6] = (bf16)v1.z; v[7] = (bf16)v1.w;
            *(bf16x8*)&As[arow * 40 + akp] = v;
        }
        // ---- stage W tile transposed: Bs[n][k]
        {
            const float* src = W + (size_t)(k0 + bk) * N + bn + bnp;
            float4 v0 = *(const float4*)src;
            float4 v1 = *(const float4*)(src + 4);
            float f[8] = {v0.x, v0.y, v0.z, v0.w, v1.x, v1.y, v1.z, v1.w};
#pragma unroll
            for (int i = 0; i < 8; i++) Bs[(bnp + i) * 40 + bk] = (bf16)f[i];
        }
        __syncthreads();

        bf16x8 af[2], bfr[2];
#pragma unroll
        for (int mt = 0; mt < 2; mt++)
            af[mt] = *(const bf16x8*)&As[(waveM + mt * 16 + l15) * 40 + quad * 8];
#pragma unroll
        for (int nt = 0; nt < 2; nt++)
            bfr[nt] = *(const bf16x8*)&Bs[(waveN + nt * 16 + l15) * 40 + quad * 8];
#pragma unroll
        for (int mt = 0; mt < 2; mt++)
#pragma unroll
            for (int nt = 0; nt < 2; nt++)
                acc[mt][nt] = MFMA_16x16x32(af[mt], bfr[nt], acc[mt][nt]);
        __syncthreads();
    }

    const int H = N >> 6;
#pragma unroll
    for (int mt = 0; mt < 2; mt++) {
#pragma unroll
        for (int nt = 0; nt < 2; nt++) {
#pragma unroll
            for (int r = 0; r < 4; r++) {
                int row = bm + waveM + mt * 16 + quad * 4 + r;
                int col = bn + waveN + nt * 16 + l15;
                float v = (acc[mt][nt][r] + bias[col]) * scale;
                if (mode == 1) {
                    ((float*)Out)[(size_t)row * N + col] = v;
                } else {
                    int b = row / S, s = row - b * S;
                    int h = col >> 6, dd = col & 63;
                    ((bf16*)Out)[(((size_t)(b * H + h)) * S + s) * 64 + dd] = (bf16)v;
                }
            }
        }
    }
}

// ---------------------------------------------------------------------------
// Flash-style causal attention. Q pre-scaled by SCALE.
// Q/K/V: bf16 [B*H, S, 64]. Out: bf16 [B, S, H*64].
// Block: 256 thr (4 waves). One block = 64 query rows of one (b,h).
// Wave w owns 16 query rows [q0+16w, q0+16w+16). Key tiles of 32.
// P round-trips through LDS for C-layout -> A-layout (m120 recipe).
// ---------------------------------------------------------------------------
__global__ __launch_bounds__(256) void attn_kernel(
    const bf16* __restrict__ Q, const bf16* __restrict__ Kg,
    const bf16* __restrict__ Vg, bf16* __restrict__ Ob,
    int S, int H)
{
    __shared__ bf16 Qs[64 * 72];      // [qrow][dim]
    __shared__ bf16 Ks[32 * 72];      // [key][dim]
    __shared__ bf16 Vt[64 * 40];      // [dim][key] (transposed V tile)
    __shared__ bf16 Ps[4][16 * 40];   // per-wave P tile [qrow][key]

    const int t = threadIdx.x;
    const int wave = t >> 6, lane = t & 63;
    const int quad = lane >> 4, l15 = lane & 15;
    const int q0 = blockIdx.x * 64;
    const int bh = blockIdx.y;

    const bf16* Qh = Q + (size_t)bh * S * 64;
    const bf16* Kh = Kg + (size_t)bh * S * 64;
    const bf16* Vh = Vg + (size_t)bh * S * 64;

    // ---- load Q tile (64x64) into LDS, then into per-wave A fragments
    {
        int row = t >> 2, kp = (t & 3) * 16;
        const bf16* src = Qh + (size_t)(q0 + row) * 64 + kp;
        *(bf16x8*)&Qs[row * 72 + kp]     = *(const bf16x8*)src;
        *(bf16x8*)&Qs[row * 72 + kp + 8] = *(const bf16x8*)(src + 8);
    }
    __syncthreads();
    bf16x8 qf[2];
    {
        int row = wave * 16 + l15;
        qf[0] = *(const bf16x8*)&Qs[row * 72 + quad * 8];
        qf[1] = *(const bf16x8*)&Qs[row * 72 + 32 + quad * 8];
    }

    floatx4 o[4] = {};
    float m_r[4], l_r[4];
#pragma unroll
    for (int r = 0; r < 4; r++) { m_r[r] = NEG_INF; l_r[r] = 0.f; }

    const int myRow0 = q0 + wave * 16;
    const int nTiles = (q0 + 64) / 32;

    for (int kt = 0; kt < nTiles; kt++) {
        const int ks0 = kt * 32;
        __syncthreads();   // previous iter's reads done before overwriting tiles
        // ---- cooperative stage: K tile row-major, V tile transposed
        {
            int key = t >> 3, dp = (t & 7) * 8;
            *(bf16x8*)&Ks[key * 72 + dp] =
                *(const bf16x8*)(Kh + (size_t)(ks0 + key) * 64 + dp);
            bf16x8 v = *(const bf16x8*)(Vh + (size_t)(ks0 + key) * 64 + dp);
#pragma unroll
            for (int i = 0; i < 8; i++) Vt[(dp + i) * 40 + key] = v[i];
        }
        __syncthreads();

        if (ks0 <= myRow0 + 15) {   // wave-uniform: tile not fully masked
            // ---- QK^T: 2 key sub-tiles x 2 k-steps over dims
            floatx4 sc[2] = {};
#pragma unroll
            for (int nt = 0; nt < 2; nt++) {
                bf16x8 kf0 = *(const bf16x8*)&Ks[(nt * 16 + l15) * 72 + quad * 8];
                bf16x8 kf1 = *(const bf16x8*)&Ks[(nt * 16 + l15) * 72 + 32 + quad * 8];
                sc[nt] = MFMA_16x16x32(qf[0], kf0, sc[nt]);
                sc[nt] = MFMA_16x16x32(qf[1], kf1, sc[nt]);
            }
            // ---- causal mask (only tiles overlapping the diagonal band)
            if (ks0 + 31 > myRow0) {
#pragma unroll
                for (int nt = 0; nt < 2; nt++)
#pragma unroll
                    for (int r = 0; r < 4; r++) {
                        int qrow = myRow0 + quad * 4 + r;
                        int kcol = ks0 + nt * 16 + l15;
                        if (kcol > qrow) sc[nt][r] = NEG_INF;
                    }
            }
            // ---- online softmax: row stats live on the 16 lanes of each quad
            float alpha[4];
#pragma unroll
            for (int r = 0; r < 4; r++) {
                float v = fmaxf(sc[0][r], sc[1][r]);
#pragma unroll
                for (int off = 1; off < 16; off <<= 1) v = fmaxf(v, __shfl_xor(v, off));
                float mn = fmaxf(m_r[r], v);
                alpha[r] = __expf(m_r[r] - mn);   // exp(-inf)=0 on first tile
                m_r[r] = mn;
            }
#pragma unroll
            for (int r = 0; r < 4; r++) {
                sc[0][r] = __expf(sc[0][r] - m_r[r]);
                sc[1][r] = __expf(sc[1][r] - m_r[r]);
                float v = sc[0][r] + sc[1][r];
#pragma unroll
                for (int off = 1; off < 16; off <<= 1) v += __shfl_xor(v, off);
                l_r[r] = l_r[r] * alpha[r] + v;
            }
#pragma unroll
            for (int dt = 0; dt < 4; dt++)
#pragma unroll
                for (int r = 0; r < 4; r++) o[dt][r] *= alpha[r];
            // ---- P: C-layout regs -> LDS -> A-layout fragment (same wave; no barrier)
            bf16* ps = Ps[wave];
#pragma unroll
            for (int nt = 0; nt < 2; nt++)
#pragma unroll
                for (int r = 0; r < 4; r++)
                    ps[(quad * 4 + r) * 40 + nt * 16 + l15] = (bf16)sc[nt][r];
            bf16x8 pf = *(const bf16x8*)&ps[l15 * 40 + quad * 8];
            // ---- PV: 4 dim sub-tiles
#pragma unroll
            for (int dt = 0; dt < 4; dt++) {
                bf16x8 vf = *(const bf16x8*)&Vt[(dt * 16 + l15) * 40 + quad * 8];
                o[dt] = MFMA_16x16x32(pf, vf, o[dt]);
            }
        }
    }

    // ---- epilogue: normalize and store to [B, S, H*64] bf16
    const int b = bh / H, h = bh - b * H;
    float rl[4];
#pragma unroll
    for (int r = 0; r < 4; r++) rl[r] = 1.f / l_r[r];
#pragma unroll
    for (int dt = 0; dt < 4; dt++)
#pragma unroll
        for (int r = 0; r < 4; r++) {
            int srow = q0 + wave * 16 + quad * 4 + r;
            int col = h * 64 + dt * 16 + l15;
            Ob[((size_t)b * S + srow) * (size_t)(H * 64) + col] = (bf16)(o[dt][r] * rl[r]);
        }
}

// ---------------------------------------------------------------------------
extern "C" void kernel_launch(void* const* d_in, const int* in_sizes, int n_in,
                              void* d_out, int out_size, void* d_ws, size_t ws_size,
                              hipStream_t stream)
{
    const float* x  = (const float*)d_in[0];
    const float* Wq = (const float*)d_in[1];
    const float* bq = (const float*)d_in[2];
    const float* Wk = (const float*)d_in[3];
    const float* bk = (const float*)d_in[4];
    const float* Wv = (const float*)d_in[5];
    const float* bv = (const float*)d_in[6];
    const float* Wo = (const float*)d_in[7];
    const float* bo = (const float*)d_in[8];
    float* out = (float*)d_out;

    const int B = 2, S = 2048, D = 1024, H = 16;
    const int M = B * S;
    const float SCALE = 0.03125f;   // DIM^-0.5 = 1/32, exact power of two

    // workspace: Q,K,V bf16 [B,H,S,64] + O bf16 [B,S,D]  => 32 MiB
    bf16* Qb = (bf16*)d_ws;
    bf16* Kb = Qb + (size_t)B * H * S * 64;
    bf16* Vb = Kb + (size_t)B * H * S * 64;
    bf16* Ob = Vb + (size_t)B * H * S * 64;

    dim3 gg(D / 64, M / 64);
    // Q pre-scaled by SCALE (exact in bf16: x * 2^-5)
    gemm_mfma<false><<<gg, 256, 0, stream>>>(x, Wq, bq, (void*)Qb, M, D, D, 0, SCALE, S);
    gemm_mfma<false><<<gg, 256, 0, stream>>>(x, Wk, bk, (void*)Kb, M, D, D, 0, 1.0f, S);
    gemm_mfma<false><<<gg, 256, 0, stream>>>(x, Wv, bv, (void*)Vb, M, D, D, 0, 1.0f, S);
    attn_kernel<<<dim3(S / 64, B * H), 256, 0, stream>>>(Qb, Kb, Vb, Ob, S, H);
    gemm_mfma<true><<<gg, 256, 0, stream>>>((void*)Ob, Wo, bo, (void*)out, M, D, D, 1, 1.0f, S);
}

// Round 2
// 264.268 us; speedup vs baseline: 1.8465x; 1.8465x over previous
//
#include <hip/hip_runtime.h>
#include <hip/hip_bf16.h>

typedef __bf16 bf16;
typedef __bf16 bf16x4 __attribute__((ext_vector_type(4)));
typedef __bf16 bf16x8 __attribute__((ext_vector_type(8)));
typedef float floatx4 __attribute__((ext_vector_type(4)));

#define MFMA_16x16x32(a, b, c) __builtin_amdgcn_mfma_f32_16x16x32_bf16((a), (b), (c), 0, 0, 0)
#define NEG_INF (-__builtin_inff())

// Problem constants (B=2, S=2048, D=1024, H=16, d=64)
#define CB 2
#define CS 2048
#define CD 1024
#define CH 16
#define CM (CB * CS)
#define CSCALE 0.03125f

// async global->LDS, 16B per lane; LDS dest = wave-uniform base + lane*16
__device__ __forceinline__ void async16(const bf16* g, bf16* l) {
    __builtin_amdgcn_global_load_lds(
        (const __attribute__((address_space(1))) void*)g,
        (__attribute__((address_space(3))) void*)l, 16, 0, 0);
}

// ---------------------------------------------------------------------------
// Prep: x fp32 -> bf16
// ---------------------------------------------------------------------------
__global__ __launch_bounds__(256) void conv_x(const float* __restrict__ x,
                                              bf16* __restrict__ xb) {
    size_t i = ((size_t)blockIdx.x * 256 + threadIdx.x) * 8;
    float4 a = *(const float4*)(x + i);
    float4 b = *(const float4*)(x + i + 4);
    bf16x8 v;
    v[0] = (bf16)a.x; v[1] = (bf16)a.y; v[2] = (bf16)a.z; v[3] = (bf16)a.w;
    v[4] = (bf16)b.x; v[5] = (bf16)b.y; v[6] = (bf16)b.z; v[7] = (bf16)b.w;
    *(bf16x8*)(xb + i) = v;
}

// ---------------------------------------------------------------------------
// Prep: W [K][N] fp32 -> Wt [N][K] bf16 (64x64 LDS tile transpose)
// grid: (N/64, K/64, 4)  — z selects which W
// ---------------------------------------------------------------------------
__global__ __launch_bounds__(256) void conv_wt(
    const float* __restrict__ W0, const float* __restrict__ W1,
    const float* __restrict__ W2, const float* __restrict__ W3,
    bf16* __restrict__ Wt) {
    __shared__ bf16 Ws[64 * 68];
    const float* W = blockIdx.z == 0 ? W0 : blockIdx.z == 1 ? W1
                   : blockIdx.z == 2 ? W2 : W3;
    bf16* out = Wt + (size_t)blockIdx.z * CD * CD;
    const int t = threadIdx.x;
    const int n0 = blockIdx.x * 64, k0 = blockIdx.y * 64;
    const int rr = t >> 4, c4 = (t & 15) * 4;
#pragma unroll
    for (int i = 0; i < 4; i++) {
        int r = rr + i * 16;
        float4 f = *(const float4*)(W + (size_t)(k0 + r) * CD + n0 + c4);
        bf16x4 v;
        v[0] = (bf16)f.x; v[1] = (bf16)f.y; v[2] = (bf16)f.z; v[3] = (bf16)f.w;
        *(bf16x4*)&Ws[r * 68 + c4] = v;
    }
    __syncthreads();
#pragma unroll
    for (int i = 0; i < 4; i++) {
        int n = rr + i * 16;
        bf16x4 v;
#pragma unroll
        for (int j = 0; j < 4; j++) v[j] = Ws[(c4 + j) * 68 + n];
        *(bf16x4*)(out + (size_t)(n0 + n) * CD + k0 + c4) = v;
    }
}

// ---------------------------------------------------------------------------
// Fused QKV GEMM (m97 structure): 128x128 tile, BK=32, global_load_lds x16B.
// A: xb bf16 [M][K]. Bt: [3][N][K] bf16 (q,k,v transposed weights).
// which = blockIdx.x>>3: 0->Q (scaled, [bh][s][64]), 1->K ([bh][s][64]),
// 2->V (transposed store [bh][64][S]).
// grid: (24, M/128), 256 threads.
// ---------------------------------------------------------------------------
__global__ __launch_bounds__(256) void gemm_qkv(
    const bf16* __restrict__ A, const bf16* __restrict__ Bt,
    const float* __restrict__ bq, const float* __restrict__ bk,
    const float* __restrict__ bv,
    bf16* __restrict__ Qb, bf16* __restrict__ Kb, bf16* __restrict__ Vb) {
    __shared__ bf16 As[128 * 32];
    __shared__ bf16 Bs[128 * 32];
    const int t = threadIdx.x, w = t >> 6, lane = t & 63;
    const int quad = lane >> 4, l15 = lane & 15;
    const int which = blockIdx.x >> 3;
    const int bn = (blockIdx.x & 7) * 128, bm = blockIdx.y * 128;
    const bf16* Bw = Bt + (size_t)which * CD * CD;

    const bf16* ag = A + (size_t)(bm + w * 16 + (lane >> 2)) * CD + (lane & 3) * 8;
    const bf16* bg = Bw + (size_t)(bn + w * 16 + (lane >> 2)) * CD + (lane & 3) * 8;
    const int lo = w * 16 * 32;   // elems; wave-uniform LDS chunk base

    const int wm = (w >> 1) * 64, wn = (w & 1) * 64;
    floatx4 acc[4][4] = {};

    for (int k0 = 0; k0 < CD; k0 += 32) {
        async16(ag + k0, &As[lo]);
        async16(ag + (size_t)64 * CD + k0, &As[lo + 64 * 32]);
        async16(bg + k0, &Bs[lo]);
        async16(bg + (size_t)64 * CD + k0, &Bs[lo + 64 * 32]);
        __syncthreads();
        bf16x8 af[4], bfr[4];
#pragma unroll
        for (int mt = 0; mt < 4; mt++)
            af[mt] = *(const bf16x8*)&As[(wm + mt * 16 + l15) * 32 + quad * 8];
#pragma unroll
        for (int nt = 0; nt < 4; nt++)
            bfr[nt] = *(const bf16x8*)&Bs[(wn + nt * 16 + l15) * 32 + quad * 8];
#pragma unroll
        for (int mt = 0; mt < 4; mt++)
#pragma unroll
            for (int nt = 0; nt < 4; nt++)
                acc[mt][nt] = MFMA_16x16x32(af[mt], bfr[nt], acc[mt][nt]);
        __syncthreads();
    }

    const float* bias = which == 0 ? bq : which == 1 ? bk : bv;
    bf16* out = which == 0 ? Qb : which == 1 ? Kb : Vb;
#pragma unroll
    for (int mt = 0; mt < 4; mt++) {
#pragma unroll
        for (int nt = 0; nt < 4; nt++) {
#pragma unroll
            for (int r = 0; r < 4; r++) {
                int row = bm + wm + mt * 16 + quad * 4 + r;   // token index
                int col = bn + wn + nt * 16 + l15;            // feature index
                float v = acc[mt][nt][r] + bias[col];
                if (which == 0) v *= CSCALE;
                int b = row >> 11, s = row & (CS - 1);
                int h = col >> 6, dd = col & 63;
                size_t idx;
                if (which == 2)  // V transposed: [bh][d][S]
                    idx = (((size_t)(b * CH + h)) * 64 + dd) * CS + s;
                else             // Q/K: [bh][S][64]
                    idx = (((size_t)(b * CH + h)) * CS + s) * 64 + dd;
                out[idx] = (bf16)v;
            }
        }
    }
}

// ---------------------------------------------------------------------------
// O-projection GEMM: 64x128 tile (512 blocks -> 2/CU), fp32 output.
// A: Ob bf16 [M][D]. Bt: Wo transposed bf16 [N][K]. grid: (8, M/64).
// ---------------------------------------------------------------------------
__global__ __launch_bounds__(256) void gemm_o(
    const bf16* __restrict__ A, const bf16* __restrict__ Bt,
    const float* __restrict__ bias, float* __restrict__ out) {
    __shared__ bf16 As[64 * 32];
    __shared__ bf16 Bs[128 * 32];
    const int t = threadIdx.x, w = t >> 6, lane = t & 63;
    const int quad = lane >> 4, l15 = lane & 15;
    const int bn = blockIdx.x * 128, bm = blockIdx.y * 64;

    const bf16* ag = A + (size_t)(bm + w * 16 + (lane >> 2)) * CD + (lane & 3) * 8;
    const bf16* bg = Bt + (size_t)(bn + w * 16 + (lane >> 2)) * CD + (lane & 3) * 8;
    const int lo = w * 16 * 32;

    const int wm = (w >> 1) * 32, wn = (w & 1) * 64;
    floatx4 acc[2][4] = {};

    for (int k0 = 0; k0 < CD; k0 += 32) {
        async16(ag + k0, &As[lo]);
        async16(bg + k0, &Bs[lo]);
        async16(bg + (size_t)64 * CD + k0, &Bs[lo + 64 * 32]);
        __syncthreads();
        bf16x8 af[2], bfr[4];
#pragma unroll
        for (int mt = 0; mt < 2; mt++)
            af[mt] = *(const bf16x8*)&As[(wm + mt * 16 + l15) * 32 + quad * 8];
#pragma unroll
        for (int nt = 0; nt < 4; nt++)
            bfr[nt] = *(const bf16x8*)&Bs[(wn + nt * 16 + l15) * 32 + quad * 8];
#pragma unroll
        for (int mt = 0; mt < 2; mt++)
#pragma unroll
            for (int nt = 0; nt < 4; nt++)
                acc[mt][nt] = MFMA_16x16x32(af[mt], bfr[nt], acc[mt][nt]);
        __syncthreads();
    }

#pragma unroll
    for (int mt = 0; mt < 2; mt++)
#pragma unroll
        for (int nt = 0; nt < 4; nt++)
#pragma unroll
            for (int r = 0; r < 4; r++) {
                int row = bm + wm + mt * 16 + quad * 4 + r;
                int col = bn + wn + nt * 16 + l15;
                out[(size_t)row * CD + col] = acc[mt][nt][r] + bias[col];
            }
}

// ---------------------------------------------------------------------------
// Flash-style causal attention, 64-key tiles.
// Q/K: bf16 [bh][S][64] (Q pre-scaled). V: bf16 [bh][64][S] (pre-transposed).
// Out: bf16 [B][S][H*64]. Block: 256 thr (4 waves) = 64 query rows.
// Reversed q-tile order for load-balance packing.
// ---------------------------------------------------------------------------
__global__ __launch_bounds__(256) void attn_kernel(
    const bf16* __restrict__ Q, const bf16* __restrict__ Kg,
    const bf16* __restrict__ Vg, bf16* __restrict__ Ob) {
    __shared__ bf16 Qs[64 * 72];      // [qrow][dim]
    __shared__ bf16 Ks[64 * 72];      // [key][dim]
    __shared__ bf16 Vt[64 * 72];      // [dim][key] straight from global
    __shared__ bf16 Ps[4][16 * 72];   // per-wave P tile [qrow][key]

    const int t = threadIdx.x;
    const int wave = t >> 6, lane = t & 63;
    const int quad = lane >> 4, l15 = lane & 15;
    const int qt = (gridDim.x - 1 - blockIdx.x);   // big tiles first
    const int q0 = qt * 64;
    const int bh = blockIdx.y;

    const bf16* Qh = Q + (size_t)bh * CS * 64;
    const bf16* Kh = Kg + (size_t)bh * CS * 64;
    const bf16* Vh = Vg + (size_t)bh * 64 * CS;

    // ---- Q tile -> LDS -> per-wave A fragments (once)
    {
        int row = t >> 2, kp = (t & 3) * 16;
        const bf16* src = Qh + (size_t)(q0 + row) * 64 + kp;
        *(bf16x8*)&Qs[row * 72 + kp]     = *(const bf16x8*)src;
        *(bf16x8*)&Qs[row * 72 + kp + 8] = *(const bf16x8*)(src + 8);
    }
    __syncthreads();
    bf16x8 qf[2];
    {
        int row = wave * 16 + l15;
        qf[0] = *(const bf16x8*)&Qs[row * 72 + quad * 8];
        qf[1] = *(const bf16x8*)&Qs[row * 72 + 32 + quad * 8];
    }

    floatx4 o[4] = {};
    float m_r[4], l_r[4];
#pragma unroll
    for (int r = 0; r < 4; r++) { m_r[r] = NEG_INF; l_r[r] = 0.f; }

    const int myRow0 = q0 + wave * 16;
    const int nTiles = qt + 1;

    for (int kt = 0; kt < nTiles; kt++) {
        const int ks0 = kt * 64;
        __syncthreads();   // previous iteration's LDS reads complete
        // ---- stage K [key][dim] and V^T [dim][key] — both contiguous vec writes
        {
            int row = t >> 2, off = (t & 3) * 16;
            const bf16* ksrc = Kh + (size_t)(ks0 + row) * 64 + off;
            *(bf16x8*)&Ks[row * 72 + off]     = *(const bf16x8*)ksrc;
            *(bf16x8*)&Ks[row * 72 + off + 8] = *(const bf16x8*)(ksrc + 8);
            const bf16* vsrc = Vh + (size_t)row * CS + ks0 + off;
            *(bf16x8*)&Vt[row * 72 + off]     = *(const bf16x8*)vsrc;
            *(bf16x8*)&Vt[row * 72 + off + 8] = *(const bf16x8*)(vsrc + 8);
        }
        __syncthreads();

        // ---- QK^T: 4 key sub-tiles x 2 k-steps = 8 MFMAs
        floatx4 sc[4] = {};
#pragma unroll
        for (int nt = 0; nt < 4; nt++) {
            bf16x8 kf0 = *(const bf16x8*)&Ks[(nt * 16 + l15) * 72 + quad * 8];
            bf16x8 kf1 = *(const bf16x8*)&Ks[(nt * 16 + l15) * 72 + 32 + quad * 8];
            sc[nt] = MFMA_16x16x32(qf[0], kf0, sc[nt]);
            sc[nt] = MFMA_16x16x32(qf[1], kf1, sc[nt]);
        }
        // ---- causal mask: only the last (diagonal) tile needs it
        if (ks0 + 63 > myRow0) {
#pragma unroll
            for (int nt = 0; nt < 4; nt++)
#pragma unroll
                for (int r = 0; r < 4; r++) {
                    int qrow = myRow0 + quad * 4 + r;
                    int kcol = ks0 + nt * 16 + l15;
                    if (kcol > qrow) sc[nt][r] = NEG_INF;
                }
        }
        // ---- online softmax (row stats across the quad's 16 lanes)
        float alpha[4];
#pragma unroll
        for (int r = 0; r < 4; r++) {
            float v = fmaxf(fmaxf(sc[0][r], sc[1][r]), fmaxf(sc[2][r], sc[3][r]));
#pragma unroll
            for (int off = 1; off < 16; off <<= 1) v = fmaxf(v, __shfl_xor(v, off));
            float mn = fmaxf(m_r[r], v);
            alpha[r] = __expf(m_r[r] - mn);
            m_r[r] = mn;
        }
#pragma unroll
        for (int r = 0; r < 4; r++) {
            float sum = 0.f;
#pragma unroll
            for (int nt = 0; nt < 4; nt++) {
                sc[nt][r] = __expf(sc[nt][r] - m_r[r]);
                sum += sc[nt][r];
            }
#pragma unroll
            for (int off = 1; off < 16; off <<= 1) sum += __shfl_xor(sum, off);
            l_r[r] = l_r[r] * alpha[r] + sum;
        }
#pragma unroll
        for (int dt = 0; dt < 4; dt++)
#pragma unroll
            for (int r = 0; r < 4; r++) o[dt][r] *= alpha[r];
        // ---- P: C-layout regs -> LDS -> A-layout fragments (same wave)
        bf16* ps = Ps[wave];
#pragma unroll
        for (int nt = 0; nt < 4; nt++)
#pragma unroll
            for (int r = 0; r < 4; r++)
                ps[(quad * 4 + r) * 72 + nt * 16 + l15] = (bf16)sc[nt][r];
        bf16x8 pf0 = *(const bf16x8*)&ps[l15 * 72 + quad * 8];
        bf16x8 pf1 = *(const bf16x8*)&ps[l15 * 72 + 32 + quad * 8];
        // ---- PV: 4 dim sub-tiles x 2 key-steps = 8 MFMAs
#pragma unroll
        for (int dt = 0; dt < 4; dt++) {
            bf16x8 vf0 = *(const bf16x8*)&Vt[(dt * 16 + l15) * 72 + quad * 8];
            bf16x8 vf1 = *(const bf16x8*)&Vt[(dt * 16 + l15) * 72 + 32 + quad * 8];
            o[dt] = MFMA_16x16x32(pf0, vf0, o[dt]);
            o[dt] = MFMA_16x16x32(pf1, vf1, o[dt]);
        }
    }

    // ---- epilogue: normalize, store [B][S][H*64]
    const int b = bh >> 4, h = bh & 15;
    float rl[4];
#pragma unroll
    for (int r = 0; r < 4; r++) rl[r] = 1.f / l_r[r];
#pragma unroll
    for (int dt = 0; dt < 4; dt++)
#pragma unroll
        for (int r = 0; r < 4; r++) {
            int srow = q0 + wave * 16 + quad * 4 + r;
            int col = h * 64 + dt * 16 + l15;
            Ob[((size_t)b * CS + srow) * CD + col] = (bf16)(o[dt][r] * rl[r]);
        }
}

// ---------------------------------------------------------------------------
extern "C" void kernel_launch(void* const* d_in, const int* in_sizes, int n_in,
                              void* d_out, int out_size, void* d_ws, size_t ws_size,
                              hipStream_t stream) {
    const float* x  = (const float*)d_in[0];
    const float* Wq = (const float*)d_in[1];
    const float* bq = (const float*)d_in[2];
    const float* Wk = (const float*)d_in[3];
    const float* bk = (const float*)d_in[4];
    const float* Wv = (const float*)d_in[5];
    const float* bv = (const float*)d_in[6];
    const float* Wo = (const float*)d_in[7];
    const float* bo = (const float*)d_in[8];
    float* out = (float*)d_out;

    // workspace layout (bf16 elems): xb[4M] Wt[4M] Qb[4M] Kb[4M] Vb[4M] Ob[4M]
    bf16* xb = (bf16*)d_ws;
    bf16* Wt = xb + (size_t)CM * CD;
    bf16* Qb = Wt + (size_t)4 * CD * CD;
    bf16* Kb = Qb + (size_t)CM * 64 * CH / CH * 1;   // = CM*64*CH? no: B*H*S*64 = CM*64*16/… keep explicit below
    // explicit:
    Qb = Wt + (size_t)4 * CD * CD;
    Kb = Qb + (size_t)CB * CH * CS * 64;
    bf16* Vb = Kb + (size_t)CB * CH * CS * 64;
    bf16* Ob = Vb + (size_t)CB * CH * CS * 64;

    // prep: x -> bf16; W{q,k,v,o} -> bf16 transposed [N][K]
    conv_x<<<(CM * CD) / (256 * 8), 256, 0, stream>>>(x, xb);
    conv_wt<<<dim3(CD / 64, CD / 64, 4), 256, 0, stream>>>(Wq, Wk, Wv, Wo, Wt);

    // fused QKV projection (768 blocks -> 3/CU)
    gemm_qkv<<<dim3(24, CM / 128), 256, 0, stream>>>(
        xb, Wt, bq, bk, bv, Qb, Kb, Vb);

    // attention (1024 blocks, big q-tiles first)
    attn_kernel<<<dim3(CS / 64, CB * CH), 256, 0, stream>>>(Qb, Kb, Vb, Ob);

    // output projection (512 blocks -> 2/CU), Wo is Wt slice 3
    gemm_o<<<dim3(8, CM / 64), 256, 0, stream>>>(
        Ob, Wt + (size_t)3 * CD * CD, bo, out);
}